// Round 10
// baseline (105.765 us; speedup 1.0000x reference)
//
#include <hip/hip_runtime.h>

// PointWarping: B=2, C=3, N=8192. Brute-force K=3 NN + inverse-distance flow interp.
// Round 10: r7 exact pipeline (direct-form distances, keys-only butterfly,
// ballot index recovery, exact epilogue) + packed-fp32 scan:
// prestage SoA pair-packed float2 arrays wx/wy/wz (wx[i] = (x[2i],x[2i+1]))
// so each dwordx2 load is a ready v2f32; distances for 2 candidates per
// v_pk_add_f32 / v_pk_fma_f32 chain — bit-identical arithmetic to r7's
// scalar sub/mul/fma. Key = trunc26(d) | 6-bit (row<<1|s); candidate index
// reconstructed from (row, s, ballot lane). NO expanded-form keys (r9 failed
// threshold by 0.3% from cancellation-induced neighbor flips).

#define NPTS   8192
#define PAIRS  (NPTS / 2)         // 4096 candidate pairs per batch
#define BLOCK  256
#define Q      4                  // queries per wave (wave-uniform)
#define QPB    8                  // queries per block (2 wave-pairs x 4)
#define HALF   4096               // candidates per wave (2-way split)
#define KMASK  0xFFFFFFC0         // keep 26 msbs of d; low 6 bits = (row<<1)|s
#define EPSV   1e-10f

typedef float v2f __attribute__((ext_vector_type(2)));

__device__ __forceinline__ v2f v2fma(v2f a, v2f b, v2f c) {
#if __has_builtin(__builtin_elementwise_fma)
    return __builtin_elementwise_fma(a, b, c);
#else
    v2f r; r.x = fmaf(a.x, b.x, c.x); r.y = fmaf(a.y, b.y, c.y); return r;
#endif
}

__device__ __forceinline__ float rfl_f32(float x) {
    // readfirstlane is b32: bit-cast, never numeric-convert
    return __int_as_float(__builtin_amdgcn_readfirstlane(__float_as_int(x)));
}

// sorted top-3 stream insert, keys only (3 VALU)
__device__ __forceinline__ void ksort3(float k, float& m0, float& m1, float& m2) {
    m2 = __builtin_amdgcn_fmed3f(k, m1, m2);
    m1 = __builtin_amdgcn_fmed3f(k, m0, m1);
    m0 = fminf(k, m0);
}

// sorted top-3 insert with index tracking (epilogue only)
__device__ __forceinline__ void insert3_idx(float k, int idx,
                                            float& m0, float& m1, float& m2,
                                            int& j0, int& j1, int& j2) {
    const bool c0 = k < m0;
    const bool c1 = k < m1;
    const bool c2 = k < m2;
    ksort3(k, m0, m1, m2);
    j2 = c1 ? j1 : (c2 ? idx : j2);
    j1 = c0 ? j0 : (c1 ? idx : j1);
    j0 = c0 ? idx : j0;
}

// pre-kernel: pair-packed SoA warped points. wx[b*PAIRS+i] = (x[2i], x[2i+1]) etc.
__global__ __launch_bounds__(256)
void warp_points_kernel(const float* __restrict__ xyz1,
                        const float* __restrict__ flow1,
                        v2f* __restrict__ wx, v2f* __restrict__ wy,
                        v2f* __restrict__ wz, int totalPairs) {
    const int i = blockIdx.x * 256 + threadIdx.x;
    if (i >= totalPairs) return;
    const int b = i / PAIRS, ip = i - b * PAIRS;
    const v2f* x1v = (const v2f*)(xyz1 + (size_t)b * 3 * NPTS);
    const v2f* f1v = (const v2f*)(flow1 + (size_t)b * 3 * NPTS);
    wx[i] = x1v[0*PAIRS + ip] + f1v[0*PAIRS + ip];
    wy[i] = x1v[1*PAIRS + ip] + f1v[1*PAIRS + ip];
    wz[i] = x1v[2*PAIRS + ip] + f1v[2*PAIRS + ip];
}

__global__ __launch_bounds__(BLOCK, 8)
void pointwarp_kernel(const v2f* __restrict__ wx, const v2f* __restrict__ wy,
                      const v2f* __restrict__ wz,
                      const float* __restrict__ xyz2,
                      const float* __restrict__ flow1,
                      float* __restrict__ out) {
    __shared__ float s_k[2][2][Q][3];
    __shared__ int   s_i[2][2][Q][3];

    const int tid  = threadIdx.x;
    const int w    = tid >> 6;              // wave in block [0,4)
    const int t    = tid & 63;              // lane
    const int pair = w >> 1;                // query-quad [0,2)
    const int w2   = w & 1;                 // candidate half [0,2)
    const int blocksPerB = NPTS / QPB;      // 1024
    const int b     = blockIdx.x / blocksPerB;
    const int qblk  = (blockIdx.x % blocksPerB) * QPB;
    const int qbase = qblk + pair * Q;

    const v2f* wxb = wx + (size_t)b * PAIRS;
    const v2f* wyb = wy + (size_t)b * PAIRS;
    const v2f* wzb = wz + (size_t)b * PAIRS;
    const float* x2 = xyz2 + (size_t)b * 3 * NPTS;
    const float* f1 = flow1 + (size_t)b * 3 * NPTS;

    // wave-uniform queries (broadcast pairs for pk math)
    v2f qx2[Q], qy2[Q], qz2[Q];
    float k0[Q], k1[Q], k2[Q];
    #pragma unroll
    for (int i = 0; i < Q; ++i) {
        const float qx = rfl_f32(x2[0*NPTS + qbase + i]);
        const float qy = rfl_f32(x2[1*NPTS + qbase + i]);
        const float qz = rfl_f32(x2[2*NPTS + qbase + i]);
        qx2[i].x = qx; qx2[i].y = qx;
        qy2[i].x = qy; qy2[i].y = qy;
        qz2[i].x = qz; qz2[i].y = qz;
        k0[i] = k1[i] = k2[i] = 3e38f;
    }

    // scan this wave's half: lane t, iter j handles candidates
    // w2*4096 + j*128 + 2t + {0,1}. 3 dwordx2 loads -> v2f32 pairs.
    const v2f* bx = wxb + w2 * (HALF/2) + t;
    const v2f* by = wyb + w2 * (HALF/2) + t;
    const v2f* bz = wzb + w2 * (HALF/2) + t;
    #pragma unroll 2
    for (int j = 0; j < HALF / 128; ++j) {      // 32 iterations
        const v2f px = bx[j * 64];
        const v2f py = by[j * 64];
        const v2f pz = bz[j * 64];
        const int js0 = j << 1;                 // (row<<1)|s, s=0
        const int js1 = js0 | 1;
        #pragma unroll
        for (int i = 0; i < Q; ++i) {
            const v2f dx = px - qx2[i];         // v_pk_add_f32
            const v2f dy = py - qy2[i];
            const v2f dz = pz - qz2[i];
            // d = fma(dx,dx, fma(dy,dy, dz*dz)) — same order as r7 scalar path
            const v2f d  = v2fma(dx, dx, v2fma(dy, dy, dz * dz));
            ksort3(__int_as_float((__float_as_int(d.x) & KMASK) | js0),
                   k0[i], k1[i], k2[i]);
            ksort3(__int_as_float((__float_as_int(d.y) & KMASK) | js1),
                   k0[i], k1[i], k2[i]);
        }
    }

    // save pre-merge per-lane top-3 keys (for index resolution)
    float a0[Q], a1[Q], a2[Q];
    #pragma unroll
    for (int i = 0; i < Q; ++i) { a0[i] = k0[i]; a1[i] = k1[i]; a2[i] = k2[i]; }

    // keys-only butterfly merge: 64 partial top-3 -> wave top-3 (all lanes)
    #pragma unroll
    for (int step = 1; step < 64; step <<= 1) {
        #pragma unroll
        for (int i = 0; i < Q; ++i) {
            const float b0 = __shfl_xor(k0[i], step, 64);
            const float b1 = __shfl_xor(k1[i], step, 64);
            const float b2 = __shfl_xor(k2[i], step, 64);
            ksort3(b0, k0[i], k1[i], k2[i]);
            ksort3(b1, k0[i], k1[i], k2[i]);
            ksort3(b2, k0[i], k1[i], k2[i]);
        }
    }

    // resolve indices: first lane whose pre-merge top-3 contains the final key.
    // cand = w2*HALF + row*128 + 2*lane + s, where key low6 = (row<<1)|s
    int i0[Q], i1[Q], i2[Q];
    #pragma unroll
    for (int i = 0; i < Q; ++i) {
        {
            const float kf = k0[i];
            const unsigned long long m = __ballot(kf == a0[i] || kf == a1[i] || kf == a2[i]);
            const int low6 = __float_as_int(kf) & 0x3F;
            i0[i] = w2*HALF + (low6 >> 1)*128 + 2*(__ffsll(m) - 1) + (low6 & 1);
        }
        {
            const float kf = k1[i];
            const unsigned long long m = __ballot(kf == a0[i] || kf == a1[i] || kf == a2[i]);
            const int low6 = __float_as_int(kf) & 0x3F;
            i1[i] = w2*HALF + (low6 >> 1)*128 + 2*(__ffsll(m) - 1) + (low6 & 1);
        }
        {
            const float kf = k2[i];
            const unsigned long long m = __ballot(kf == a0[i] || kf == a1[i] || kf == a2[i]);
            const int low6 = __float_as_int(kf) & 0x3F;
            i2[i] = w2*HALF + (low6 >> 1)*128 + 2*(__ffsll(m) - 1) + (low6 & 1);
        }
    }

    // publish wave results (all lanes identical; lane i writes query i)
    #pragma unroll
    for (int i = 0; i < Q; ++i) {
        if (t == i) {
            s_k[pair][w2][i][0] = k0[i]; s_i[pair][w2][i][0] = i0[i];
            s_k[pair][w2][i][1] = k1[i]; s_i[pair][w2][i][1] = i1[i];
            s_k[pair][w2][i][2] = k2[i]; s_i[pair][w2][i][2] = i2[i];
        }
    }
    __syncthreads();

    // one thread per query: merge the two halves, exact weights, write
    if (tid < QPB) {
        const int u  = tid;
        const int pr = u >> 2, qi = u & 3;
        float m0 = 3e38f, m1 = 3e38f, m2 = 3e38f;
        int   j0 = 0, j1 = 0, j2 = 0;
        #pragma unroll
        for (int wv = 0; wv < 2; ++wv) {
            #pragma unroll
            for (int s = 0; s < 3; ++s) {
                insert3_idx(s_k[pr][wv][qi][s], s_i[pr][wv][qi][s],
                            m0, m1, m2, j0, j1, j2);
            }
        }
        // flat-float views: ((float*)wxb)[n] = x-coord of candidate n
        const float* cx = (const float*)wxb;
        const float* cy = (const float*)wyb;
        const float* cz = (const float*)wzb;
        const int n2 = qblk + u;
        const float gx = x2[0*NPTS + n2];
        const float gy = x2[1*NPTS + n2];
        const float gz = x2[2*NPTS + n2];
        float dd[3];
        const int js[3] = {j0, j1, j2};
        #pragma unroll
        for (int s = 0; s < 3; ++s) {
            const int jn = js[s];
            const float dx = cx[jn] - gx, dy = cy[jn] - gy, dz = cz[jn] - gz;
            dd[s] = fmaf(dx, dx, fmaf(dy, dy, dz*dz));   // exact direct form
        }
        float w0 = 1.0f / fmaxf(sqrtf(dd[0]), EPSV);
        float w1 = 1.0f / fmaxf(sqrtf(dd[1]), EPSV);
        float w2v = 1.0f / fmaxf(sqrtf(dd[2]), EPSV);
        const float ws = w0 + w1 + w2v;
        w0 /= ws; w1 /= ws; w2v /= ws;

        float* o = out + (size_t)b * 3 * NPTS;
        #pragma unroll
        for (int c = 0; c < 3; ++c) {
            const float fl = w0  * f1[c*NPTS + j0]
                           + w1  * f1[c*NPTS + j1]
                           + w2v * f1[c*NPTS + j2];
            o[c*NPTS + n2] = x2[c*NPTS + n2] - fl;
        }
    }
}

extern "C" void kernel_launch(void* const* d_in, const int* in_sizes, int n_in,
                              void* d_out, int out_size, void* d_ws, size_t ws_size,
                              hipStream_t stream) {
    const float* xyz1  = (const float*)d_in[0];
    const float* xyz2  = (const float*)d_in[1];
    const float* flow1 = (const float*)d_in[2];
    float* out = (float*)d_out;

    const int B = in_sizes[0] / (3 * NPTS);       // = 2
    const int totalPairs = B * PAIRS;
    v2f* wx = (v2f*)d_ws;                          // B*PAIRS pairs each
    v2f* wy = wx + totalPairs;
    v2f* wz = wy + totalPairs;

    warp_points_kernel<<<(totalPairs + 255) / 256, 256, 0, stream>>>(
        xyz1, flow1, wx, wy, wz, totalPairs);
    const int grid = B * (NPTS / QPB);            // 2048 blocks = 8 per CU
    pointwarp_kernel<<<grid, BLOCK, 0, stream>>>(wx, wy, wz, xyz2, flow1, out);
}

// Round 11
// 104.257 us; speedup vs baseline: 1.0145x; 1.0145x over previous
//
#include <hip/hip_runtime.h>

// PointWarping: B=2, C=3, N=8192. Brute-force K=3 NN + inverse-distance flow interp.
// Round 11: r7 load structure (2 streams, single-base, validated lowest-stall)
// + r10 packed-fp32 math (validated exact + VALU cut). Pair-packed prestage:
//   wxy4[p] = (x[2p], x[2p+1], y[2p], y[2p+1])  -> one dwordx4
//   wz2[p]  = (z[2p], z[2p+1])                  -> one dwordx2
// Per candidate-pair per query: 6 pk-arith + 2 and_or + 6 med3 = 7 ops/eval
// (vs 10 scalar in r7). pk_add/pk_fma are IEEE-identical to scalar: exact
// direct-form selection (expanded-form keys remain banned per r9).
// Key = trunc26(d) | 6-bit (row<<1|s); index recovery via ballot (r10-validated).

#define NPTS   8192
#define PAIRS  4096               // candidate pairs per batch
#define BLOCK  256
#define Q      4                  // queries per wave (wave-uniform)
#define QPB    8                  // queries per block (2 wave-pairs x 4)
#define HALF   4096               // candidates per wave (2-way split)
#define HPAIR  2048               // pairs per half
#define KMASK  0xFFFFFFC0         // keep 26 msbs of d; low 6 bits = (row<<1)|s
#define EPSV   1e-10f

typedef float v2f __attribute__((ext_vector_type(2)));
typedef float v4f __attribute__((ext_vector_type(4)));

__device__ __forceinline__ v2f v2fma(v2f a, v2f b, v2f c) {
#if __has_builtin(__builtin_elementwise_fma)
    return __builtin_elementwise_fma(a, b, c);
#else
    v2f r; r.x = fmaf(a.x, b.x, c.x); r.y = fmaf(a.y, b.y, c.y); return r;
#endif
}

__device__ __forceinline__ float rfl_f32(float x) {
    // readfirstlane is b32: bit-cast, never numeric-convert
    return __int_as_float(__builtin_amdgcn_readfirstlane(__float_as_int(x)));
}

// sorted top-3 stream insert, keys only (3 VALU)
__device__ __forceinline__ void ksort3(float k, float& m0, float& m1, float& m2) {
    m2 = __builtin_amdgcn_fmed3f(k, m1, m2);
    m1 = __builtin_amdgcn_fmed3f(k, m0, m1);
    m0 = fminf(k, m0);
}

// sorted top-3 insert with index tracking (epilogue only)
__device__ __forceinline__ void insert3_idx(float k, int idx,
                                            float& m0, float& m1, float& m2,
                                            int& j0, int& j1, int& j2) {
    const bool c0 = k < m0;
    const bool c1 = k < m1;
    const bool c2 = k < m2;
    ksort3(k, m0, m1, m2);
    j2 = c1 ? j1 : (c2 ? idx : j2);
    j1 = c0 ? j0 : (c1 ? idx : j1);
    j0 = c0 ? idx : j0;
}

// pre-kernel: pair-packed warped points.
// wxy4[b*PAIRS+p] = (x[2p], x[2p+1], y[2p], y[2p+1]); wz2[b*PAIRS+p] = (z[2p], z[2p+1])
__global__ __launch_bounds__(256)
void warp_points_kernel(const float* __restrict__ xyz1,
                        const float* __restrict__ flow1,
                        v4f* __restrict__ wxy4, v2f* __restrict__ wz2,
                        int totalPairs) {
    const int i = blockIdx.x * 256 + threadIdx.x;
    if (i >= totalPairs) return;
    const int b = i / PAIRS, ip = i - b * PAIRS;
    const v2f* x1v = (const v2f*)(xyz1 + (size_t)b * 3 * NPTS);
    const v2f* f1v = (const v2f*)(flow1 + (size_t)b * 3 * NPTS);
    const v2f xp = x1v[0*PAIRS + ip] + f1v[0*PAIRS + ip];
    const v2f yp = x1v[1*PAIRS + ip] + f1v[1*PAIRS + ip];
    const v2f zp = x1v[2*PAIRS + ip] + f1v[2*PAIRS + ip];
    v4f w; w.x = xp.x; w.y = xp.y; w.z = yp.x; w.w = yp.y;
    wxy4[i] = w;
    wz2[i]  = zp;
}

__global__ __launch_bounds__(BLOCK, 8)
void pointwarp_kernel(const v4f* __restrict__ wxy4, const v2f* __restrict__ wz2,
                      const float* __restrict__ xyz2,
                      const float* __restrict__ flow1,
                      float* __restrict__ out) {
    __shared__ float s_k[2][2][Q][3];
    __shared__ int   s_i[2][2][Q][3];

    const int tid  = threadIdx.x;
    const int w    = tid >> 6;              // wave in block [0,4)
    const int t    = tid & 63;              // lane
    const int pair = w >> 1;                // query-quad [0,2)
    const int w2   = w & 1;                 // candidate half [0,2)
    const int blocksPerB = NPTS / QPB;      // 1024
    const int b     = blockIdx.x / blocksPerB;
    const int qblk  = (blockIdx.x % blocksPerB) * QPB;
    const int qbase = qblk + pair * Q;

    const v4f* wxyb = wxy4 + (size_t)b * PAIRS;
    const v2f* wzb  = wz2  + (size_t)b * PAIRS;
    const float* x2 = xyz2 + (size_t)b * 3 * NPTS;
    const float* f1 = flow1 + (size_t)b * 3 * NPTS;

    // wave-uniform queries (broadcast pairs for pk math)
    v2f qx2[Q], qy2[Q], qz2[Q];
    float k0[Q], k1[Q], k2[Q];
    #pragma unroll
    for (int i = 0; i < Q; ++i) {
        const float qx = rfl_f32(x2[0*NPTS + qbase + i]);
        const float qy = rfl_f32(x2[1*NPTS + qbase + i]);
        const float qz = rfl_f32(x2[2*NPTS + qbase + i]);
        qx2[i].x = qx; qx2[i].y = qx;
        qy2[i].x = qy; qy2[i].y = qy;
        qz2[i].x = qz; qz2[i].y = qz;
        k0[i] = k1[i] = k2[i] = 3e38f;
    }

    // scan this wave's half: lane t, iter j handles pair (w2*HPAIR + j*64 + t)
    // = candidates w2*HALF + j*128 + 2t + {0,1}. Loads: 1 dwordx4 + 1 dwordx2.
    const v4f* bxy = wxyb + w2 * HPAIR + t;
    const v2f* bz  = wzb  + w2 * HPAIR + t;
    #pragma unroll 4
    for (int j = 0; j < HPAIR / 64; ++j) {      // 32 iterations
        const v4f xy = bxy[j * 64];
        const v2f zz = bz[j * 64];
        const v2f px = __builtin_shufflevector(xy, xy, 0, 1);
        const v2f py = __builtin_shufflevector(xy, xy, 2, 3);
        const int js0 = j << 1;                 // (row<<1)|s, s=0
        const int js1 = js0 | 1;
        #pragma unroll
        for (int i = 0; i < Q; ++i) {
            const v2f dx = px - qx2[i];         // v_pk_add_f32
            const v2f dy = py - qy2[i];
            const v2f dz = zz - qz2[i];
            // d = fma(dx,dx, fma(dy,dy, dz*dz)) — IEEE-identical to scalar path
            const v2f d  = v2fma(dx, dx, v2fma(dy, dy, dz * dz));
            ksort3(__int_as_float((__float_as_int(d.x) & KMASK) | js0),
                   k0[i], k1[i], k2[i]);
            ksort3(__int_as_float((__float_as_int(d.y) & KMASK) | js1),
                   k0[i], k1[i], k2[i]);
        }
    }

    // save pre-merge per-lane top-3 keys (for index resolution)
    float a0[Q], a1[Q], a2[Q];
    #pragma unroll
    for (int i = 0; i < Q; ++i) { a0[i] = k0[i]; a1[i] = k1[i]; a2[i] = k2[i]; }

    // keys-only butterfly merge: 64 partial top-3 -> wave top-3 (all lanes)
    #pragma unroll
    for (int step = 1; step < 64; step <<= 1) {
        #pragma unroll
        for (int i = 0; i < Q; ++i) {
            const float b0 = __shfl_xor(k0[i], step, 64);
            const float b1 = __shfl_xor(k1[i], step, 64);
            const float b2 = __shfl_xor(k2[i], step, 64);
            ksort3(b0, k0[i], k1[i], k2[i]);
            ksort3(b1, k0[i], k1[i], k2[i]);
            ksort3(b2, k0[i], k1[i], k2[i]);
        }
    }

    // resolve indices: first lane whose pre-merge top-3 contains the final key.
    // cand = w2*HALF + row*128 + 2*lane + s, where key low6 = (row<<1)|s
    int i0[Q], i1[Q], i2[Q];
    #pragma unroll
    for (int i = 0; i < Q; ++i) {
        {
            const float kf = k0[i];
            const unsigned long long m = __ballot(kf == a0[i] || kf == a1[i] || kf == a2[i]);
            const int low6 = __float_as_int(kf) & 0x3F;
            i0[i] = w2*HALF + (low6 >> 1)*128 + 2*(__ffsll(m) - 1) + (low6 & 1);
        }
        {
            const float kf = k1[i];
            const unsigned long long m = __ballot(kf == a0[i] || kf == a1[i] || kf == a2[i]);
            const int low6 = __float_as_int(kf) & 0x3F;
            i1[i] = w2*HALF + (low6 >> 1)*128 + 2*(__ffsll(m) - 1) + (low6 & 1);
        }
        {
            const float kf = k2[i];
            const unsigned long long m = __ballot(kf == a0[i] || kf == a1[i] || kf == a2[i]);
            const int low6 = __float_as_int(kf) & 0x3F;
            i2[i] = w2*HALF + (low6 >> 1)*128 + 2*(__ffsll(m) - 1) + (low6 & 1);
        }
    }

    // publish wave results (all lanes identical; lane i writes query i)
    #pragma unroll
    for (int i = 0; i < Q; ++i) {
        if (t == i) {
            s_k[pair][w2][i][0] = k0[i]; s_i[pair][w2][i][0] = i0[i];
            s_k[pair][w2][i][1] = k1[i]; s_i[pair][w2][i][1] = i1[i];
            s_k[pair][w2][i][2] = k2[i]; s_i[pair][w2][i][2] = i2[i];
        }
    }
    __syncthreads();

    // one thread per query: merge the two halves, exact weights, write
    if (tid < QPB) {
        const int u  = tid;
        const int pr = u >> 2, qi = u & 3;
        float m0 = 3e38f, m1 = 3e38f, m2 = 3e38f;
        int   j0 = 0, j1 = 0, j2 = 0;
        #pragma unroll
        for (int wv = 0; wv < 2; ++wv) {
            #pragma unroll
            for (int s = 0; s < 3; ++s) {
                insert3_idx(s_k[pr][wv][qi][s], s_i[pr][wv][qi][s],
                            m0, m1, m2, j0, j1, j2);
            }
        }
        // coordinate fetch from packed arrays:
        // x of cand n: ((float*)wxyb)[4*(n>>1) + (n&1)]
        // y of cand n: ((float*)wxyb)[4*(n>>1) + 2 + (n&1)]
        // z of cand n: ((float*)wzb)[n]
        const float* cxy = (const float*)wxyb;
        const float* cz  = (const float*)wzb;
        const int n2 = qblk + u;
        const float gx = x2[0*NPTS + n2];
        const float gy = x2[1*NPTS + n2];
        const float gz = x2[2*NPTS + n2];
        float dd[3];
        const int js[3] = {j0, j1, j2};
        #pragma unroll
        for (int s = 0; s < 3; ++s) {
            const int jn = js[s];
            const int p4 = 4*(jn >> 1) + (jn & 1);
            const float dx = cxy[p4]     - gx;
            const float dy = cxy[p4 + 2] - gy;
            const float dz = cz[jn]      - gz;
            dd[s] = fmaf(dx, dx, fmaf(dy, dy, dz*dz));   // exact direct form
        }
        float w0 = 1.0f / fmaxf(sqrtf(dd[0]), EPSV);
        float w1 = 1.0f / fmaxf(sqrtf(dd[1]), EPSV);
        float w2v = 1.0f / fmaxf(sqrtf(dd[2]), EPSV);
        const float ws = w0 + w1 + w2v;
        w0 /= ws; w1 /= ws; w2v /= ws;

        float* o = out + (size_t)b * 3 * NPTS;
        #pragma unroll
        for (int c = 0; c < 3; ++c) {
            const float fl = w0  * f1[c*NPTS + j0]
                           + w1  * f1[c*NPTS + j1]
                           + w2v * f1[c*NPTS + j2];
            o[c*NPTS + n2] = x2[c*NPTS + n2] - fl;
        }
    }
}

extern "C" void kernel_launch(void* const* d_in, const int* in_sizes, int n_in,
                              void* d_out, int out_size, void* d_ws, size_t ws_size,
                              hipStream_t stream) {
    const float* xyz1  = (const float*)d_in[0];
    const float* xyz2  = (const float*)d_in[1];
    const float* flow1 = (const float*)d_in[2];
    float* out = (float*)d_out;

    const int B = in_sizes[0] / (3 * NPTS);       // = 2
    const int totalPairs = B * PAIRS;
    v4f* wxy4 = (v4f*)d_ws;                        // totalPairs * 16 B
    v2f* wz2  = (v2f*)(wxy4 + totalPairs);         // totalPairs * 8 B

    warp_points_kernel<<<(totalPairs + 255) / 256, 256, 0, stream>>>(
        xyz1, flow1, wxy4, wz2, totalPairs);
    const int grid = B * (NPTS / QPB);            // 2048 blocks = 8 per CU
    pointwarp_kernel<<<grid, BLOCK, 0, stream>>>(wxy4, wz2, xyz2, flow1, out);
}